// Round 2
// baseline (915.344 us; speedup 1.0000x reference)
//
#include <hip/hip_runtime.h>

typedef unsigned short u16;
typedef unsigned int u32;

#define DEV __device__ __forceinline__

DEV float bf2f(u16 x){ u32 u=((u32)x)<<16; float f; __builtin_memcpy(&f,&u,4); return f; }
DEV u16 f2bf(float f){ u32 u; __builtin_memcpy(&u,&f,4); u32 r=u+0x7FFFu+((u>>16)&1u); return (u16)(r>>16); }
DEV void unpack8(uint4 v, float* f){
  f[0]=bf2f((u16)(v.x&0xffffu)); f[1]=bf2f((u16)(v.x>>16));
  f[2]=bf2f((u16)(v.y&0xffffu)); f[3]=bf2f((u16)(v.y>>16));
  f[4]=bf2f((u16)(v.z&0xffffu)); f[5]=bf2f((u16)(v.z>>16));
  f[6]=bf2f((u16)(v.w&0xffffu)); f[7]=bf2f((u16)(v.w>>16));
}
DEV uint4 pack8(const float* f){
  uint4 v;
  v.x=(u32)f2bf(f[0])|((u32)f2bf(f[1])<<16);
  v.y=(u32)f2bf(f[2])|((u32)f2bf(f[3])<<16);
  v.z=(u32)f2bf(f[4])|((u32)f2bf(f[5])<<16);
  v.w=(u32)f2bf(f[6])|((u32)f2bf(f[7])<<16);
  return v;
}
DEV float sigm(float x){ return 1.0f/(1.0f+__expf(-x)); }

// ---------------------------------------------------------------------------
// K1: per-token rmsnorm -> s, r (bf16), lr = sigmoid(s@W_step), gate = sigmoid(r@W_gate)
// one wave per token
// ---------------------------------------------------------------------------
__global__ __launch_bounds__(256) void k_token(const float* __restrict__ seq,
    const float* __restrict__ gs, const float* __restrict__ gr,
    const float* __restrict__ Wstep, const float* __restrict__ Wgate,
    u16* __restrict__ s, u16* __restrict__ r,
    float* __restrict__ lr, float* __restrict__ gate)
{
  int wv = threadIdx.x >> 6, lane = threadIdx.x & 63;
  int token = blockIdx.x*4 + wv;
  const float* row = seq + (size_t)token*512;
  float x[8];
  *(float4*)&x[0] = *(const float4*)(row + lane*8);
  *(float4*)&x[4] = *(const float4*)(row + lane*8 + 4);
  float ss = 0.f;
  #pragma unroll
  for (int j=0;j<8;j++) ss += x[j]*x[j];
  #pragma unroll
  for (int o=32;o>=1;o>>=1) ss += __shfl_xor(ss, o, 64);
  float inv = rsqrtf(ss*(1.0f/512.0f) + 1e-6f);
  float al[4] = {0,0,0,0}, ag[4] = {0,0,0,0};
  float sv8[8], rv8[8];
  #pragma unroll
  for (int j=0;j<8;j++){
    int d = lane*8 + j;
    float sn = x[j]*inv;
    float sv = sn*gs[d];
    float rv = sn*gr[d];
    sv8[j]=sv; rv8[j]=rv;
    float4 wst = *(const float4*)(Wstep + d*4);
    float4 wgt = *(const float4*)(Wgate + d*4);
    al[0]+=sv*wst.x; al[1]+=sv*wst.y; al[2]+=sv*wst.z; al[3]+=sv*wst.w;
    ag[0]+=rv*wgt.x; ag[1]+=rv*wgt.y; ag[2]+=rv*wgt.z; ag[3]+=rv*wgt.w;
  }
  *(uint4*)(s + (size_t)token*512 + lane*8) = pack8(sv8);
  *(uint4*)(r + (size_t)token*512 + lane*8) = pack8(rv8);
  #pragma unroll
  for (int o=32;o>=1;o>>=1){
    #pragma unroll
    for (int h=0;h<4;h++){ al[h] += __shfl_xor(al[h], o, 64); ag[h] += __shfl_xor(ag[h], o, 64); }
  }
  if (lane == 0){
    #pragma unroll
    for (int h=0;h<4;h++){
      lr[(size_t)token*4 + h]   = sigm(al[h]);
      gate[(size_t)token*4 + h] = sigm(ag[h]);
    }
  }
}

// ---------------------------------------------------------------------------
// K2: chunk means -> decay/mom gates. one block per (b, chunk)
// ---------------------------------------------------------------------------
__global__ __launch_bounds__(256) void k_chunk(const u16* __restrict__ s,
    const float* __restrict__ Wdec, const float* __restrict__ Wmom,
    float* __restrict__ momv, float* __restrict__ dgv)
{
  int b = blockIdx.x >> 6, ci = blockIdx.x & 63;
  int d = threadIdx.x;
  size_t base = ((size_t)b*4096 + (size_t)ci*64)*512;
  float a0 = 0.f, a1 = 0.f;
  #pragma unroll 4
  for (int t=0;t<64;t++){
    a0 += bf2f(s[base + (size_t)t*512 + d]);
    a1 += bf2f(s[base + (size_t)t*512 + d + 256]);
  }
  a0 *= (1.0f/64.0f); a1 *= (1.0f/64.0f);
  __shared__ float red[8][256];
  #pragma unroll
  for (int h=0;h<4;h++){
    red[h][d]   = a0*Wdec[d*4+h] + a1*Wdec[(d+256)*4+h];
    red[4+h][d] = a0*Wmom[d*4+h] + a1*Wmom[(d+256)*4+h];
  }
  __syncthreads();
  if (d < 8){
    float sum = 0.f;
    #pragma unroll 8
    for (int k=0;k<256;k++) sum += red[d][k];
    int h = d & 3;
    if (d < 4) dgv[((size_t)(b*4+h))*64 + ci] = 1.0f - sigm(sum);
    else       momv[((size_t)(b*4+h))*64 + ci] = sigm(sum);
  }
}

// ---------------------------------------------------------------------------
// K3: GEMM  C[M,N] = A[M,K](bf16) @ B[K,N](fp32).  128x128 tile, 8x8 micro, TK=16.
// OUT_BF: C bf16, else fp32.  grid = (N/128, M/128), 256 threads.
// ---------------------------------------------------------------------------
template<bool OUT_BF>
__global__ __launch_bounds__(256) void k_gemm(const u16* __restrict__ A,
    const float* __restrict__ B, void* __restrict__ Cv,
    int K, int lda, int ldb, int ldc)
{
  __shared__ float As[16][132];
  __shared__ float Bs[16][132];
  const int tid = threadIdx.x;
  const int tx = tid & 15, ty = tid >> 4;
  const int bx = blockIdx.x, by = blockIdx.y;
  const int ar = tid >> 1, ah = (tid & 1)*8;
  const int bk = tid >> 5, bc = (tid & 31)*4;
  const u16* Aptr = A + (size_t)(by*128 + ar)*lda + ah;
  const float* Bptr = B + (size_t)bk*ldb + bx*128 + bc;
  float acc[8][8] = {};
  for (int kt = 0; kt < K; kt += 16){
    uint4 av16 = *(const uint4*)(Aptr + kt);
    float af[8]; unpack8(av16, af);
    float4 b0 = *(const float4*)(Bptr + (size_t)kt*ldb);
    float4 b1 = *(const float4*)(Bptr + (size_t)(kt+8)*ldb);
    __syncthreads();
    #pragma unroll
    for (int j=0;j<8;j++) As[ah+j][ar] = af[j];
    *(float4*)&Bs[bk][bc]   = b0;
    *(float4*)&Bs[bk+8][bc] = b1;
    __syncthreads();
    #pragma unroll
    for (int kk=0;kk<16;kk++){
      float av[8], bv[8];
      *(float4*)&av[0] = *(const float4*)&As[kk][ty*8];
      *(float4*)&av[4] = *(const float4*)&As[kk][ty*8+4];
      *(float4*)&bv[0] = *(const float4*)&Bs[kk][tx*8];
      *(float4*)&bv[4] = *(const float4*)&Bs[kk][tx*8+4];
      #pragma unroll
      for (int im=0;im<8;im++)
        #pragma unroll
        for (int jn=0;jn<8;jn++)
          acc[im][jn] = fmaf(av[im], bv[jn], acc[im][jn]);
    }
  }
  #pragma unroll
  for (int im=0;im<8;im++){
    size_t off = (size_t)(by*128 + ty*8 + im)*ldc + bx*128 + tx*8;
    if (OUT_BF){
      *(uint4*)((u16*)Cv + off) = pack8(&acc[im][0]);
    } else {
      *(float4*)((float*)Cv + off)     = *(float4*)&acc[im][0];
      *(float4*)((float*)Cv + off + 4) = *(float4*)&acc[im][4];
    }
  }
}

// ---------------------------------------------------------------------------
// K4: per-chunk gradient w.r.t. fixed (M_W1, M_W2). one block per (bh, chunk).
// LDS ~104 KB. silu' kept in registers.
// ---------------------------------------------------------------------------
__global__ __launch_bounds__(256) void k_grad(const u16* __restrict__ kv,
    const float* __restrict__ lr, const float* __restrict__ W1g,
    const float* __restrict__ W2g, u16* __restrict__ s1, u16* __restrict__ s2)
{
  __shared__ u16 kcs[64][136];
  __shared__ u16 As [64][136];
  __shared__ u16 dPs[64][136];
  __shared__ u16 dHs[64][136];
  __shared__ u16 Ws [128][136];
  const int blk = blockIdx.x;
  const int bhi = blk >> 6, ci = blk & 63;
  const int b = bhi >> 2, hd = bhi & 3;
  const int tid = threadIdx.x;
  const size_t rowbase = (size_t)b*4096 + (size_t)ci*64;

  // stage kc (direct bf16 copy) and Ws <- bf16(W1)
  #pragma unroll
  for (int rep=0;rep<4;rep++){
    int lin = rep*2048 + tid*8;
    int i = lin >> 7, d = lin & 127;
    *(uint4*)&kcs[i][d] = *(const uint4*)(kv + (rowbase + i)*1024 + hd*128 + d);
  }
  #pragma unroll
  for (int rep=0;rep<8;rep++){
    int lin = rep*2048 + tid*8;
    float f[8];
    *(float4*)&f[0] = *(const float4*)(W1g + lin);
    *(float4*)&f[4] = *(const float4*)(W1g + lin + 4);
    *(uint4*)&Ws[lin>>7][lin&127] = pack8(f);
  }
  __syncthreads();

  const int i = tid >> 2, jg = tid & 3;
  float spv[4][8];   // silu'(H), stays in registers

  // H = kc @ W1 ; A = silu(H)
  {
    float acc[4][8] = {};
    #pragma unroll 2
    for (int d=0; d<128; d++){
      float a = bf2f(kcs[i][d]);
      #pragma unroll
      for (int qg=0;qg<4;qg++){
        float w[8]; unpack8(*(const uint4*)&Ws[d][qg*32+jg*8], w);
        #pragma unroll
        for (int jv=0;jv<8;jv++) acc[qg][jv] = fmaf(a, w[jv], acc[qg][jv]);
      }
    }
    #pragma unroll
    for (int qg=0;qg<4;qg++){
      float av[8];
      #pragma unroll
      for (int jv=0;jv<8;jv++){
        float h = acc[qg][jv];
        float sg = sigm(h);
        av[jv]      = h*sg;
        spv[qg][jv] = sg*(1.0f + h*(1.0f - sg));
      }
      *(uint4*)&As[i][qg*32+jg*8] = pack8(av);
    }
  }
  __syncthreads();
  // restage Ws <- bf16(W2)
  #pragma unroll
  for (int rep=0;rep<8;rep++){
    int lin = rep*2048 + tid*8;
    float f[8];
    *(float4*)&f[0] = *(const float4*)(W2g + lin);
    *(float4*)&f[4] = *(const float4*)(W2g + lin + 4);
    *(uint4*)&Ws[lin>>7][lin&127] = pack8(f);
  }
  __syncthreads();

  // P = A @ W2 ; dP = (2/128)*lr*(P - v)
  {
    float acc[4][8] = {};
    #pragma unroll 2
    for (int d=0; d<128; d++){
      float a = bf2f(As[i][d]);
      #pragma unroll
      for (int qg=0;qg<4;qg++){
        float w[8]; unpack8(*(const uint4*)&Ws[d][qg*32+jg*8], w);
        #pragma unroll
        for (int jv=0;jv<8;jv++) acc[qg][jv] = fmaf(a, w[jv], acc[qg][jv]);
      }
    }
    float lri = lr[(rowbase + i)*4 + hd] * (2.0f/128.0f);
    #pragma unroll
    for (int qg=0;qg<4;qg++){
      float vf[8];
      unpack8(*(const uint4*)(kv + (rowbase + i)*1024 + 512 + hd*128 + qg*32 + jg*8), vf);
      float dp[8];
      #pragma unroll
      for (int jv=0;jv<8;jv++) dp[jv] = lri*(acc[qg][jv] - vf[jv]);
      *(uint4*)&dPs[i][qg*32+jg*8] = pack8(dp);
    }
  }
  __syncthreads();

  // dA = dP @ W2^T ; dH = dA * silu'(H)
  {
    float acc[4][8] = {};
    #pragma unroll 1
    for (int bb=0; bb<16; bb++){
      float dp[8];
      unpack8(*(const uint4*)&dPs[i][bb*8], dp);
      #pragma unroll
      for (int qg=0;qg<4;qg++){
        #pragma unroll
        for (int jv=0;jv<8;jv++){
          int j = qg*32 + jg*8 + jv;
          float w[8]; unpack8(*(const uint4*)&Ws[j][bb*8], w);
          #pragma unroll
          for (int t=0;t<8;t++) acc[qg][jv] = fmaf(dp[t], w[t], acc[qg][jv]);
        }
      }
    }
    #pragma unroll
    for (int qg=0;qg<4;qg++){
      float dh[8];
      #pragma unroll
      for (int jv=0;jv<8;jv++) dh[jv] = spv[qg][jv]*acc[qg][jv];
      *(uint4*)&dHs[i][qg*32+jg*8] = pack8(dh);
    }
  }
  __syncthreads();

  // s2 = -(A^T @ dP) ; s1 = -(kc^T @ dH)
  const int ag = tid >> 4, bg = tid & 15;
  const size_t outbase = (size_t)blk * 16384;
  {
    float accg[8][8] = {};
    #pragma unroll 2
    for (int ii=0; ii<64; ii++){
      float a8[8], d8[8];
      unpack8(*(const uint4*)&As[ii][ag*8], a8);
      unpack8(*(const uint4*)&dPs[ii][bg*8], d8);
      #pragma unroll
      for (int aa=0;aa<8;aa++)
        #pragma unroll
        for (int cc=0;cc<8;cc++)
          accg[aa][cc] = fmaf(a8[aa], d8[cc], accg[aa][cc]);
    }
    #pragma unroll
    for (int aa=0;aa<8;aa++){
      float o[8];
      #pragma unroll
      for (int cc=0;cc<8;cc++) o[cc] = -accg[aa][cc];
      *(uint4*)(s2 + outbase + (size_t)(ag*8+aa)*128 + bg*8) = pack8(o);
    }
  }
  {
    float accg[8][8] = {};
    #pragma unroll 2
    for (int ii=0; ii<64; ii++){
      float a8[8], d8[8];
      unpack8(*(const uint4*)&kcs[ii][ag*8], a8);
      unpack8(*(const uint4*)&dHs[ii][bg*8], d8);
      #pragma unroll
      for (int aa=0;aa<8;aa++)
        #pragma unroll
        for (int cc=0;cc<8;cc++)
          accg[aa][cc] = fmaf(a8[aa], d8[cc], accg[aa][cc]);
    }
    #pragma unroll
    for (int aa=0;aa<8;aa++){
      float o[8];
      #pragma unroll
      for (int cc=0;cc<8;cc++) o[cc] = -accg[aa][cc];
      *(uint4*)(s1 + outbase + (size_t)(ag*8+aa)*128 + bg*8) = pack8(o);
    }
  }
}

// ---------------------------------------------------------------------------
// K5: fused momentum + decay scans. w1c aliases s1, w2c aliases s2 (read-then-write).
// ---------------------------------------------------------------------------
__global__ __launch_bounds__(256) void k_scan(const float* __restrict__ momv,
    const float* __restrict__ dgv, const float* __restrict__ MW1,
    const float* __restrict__ MW2, u16* __restrict__ s1w, u16* __restrict__ s2w)
{
  int bhi = blockIdx.x >> 6, eb = blockIdx.x & 63;
  int e = eb*256 + threadIdx.x;
  float u1 = MW1[e], m1 = 0.f, u2 = MW2[e], m2 = 0.f;
  size_t base = (size_t)bhi*64*16384 + e;
  #pragma unroll 1
  for (int t=0; t<64; t++){
    float g  = momv[bhi*64 + t];
    float dg = dgv[bhi*64 + t];
    size_t idx = base + (size_t)t*16384;
    float g1v = bf2f(s1w[idx]);
    float g2v = bf2f(s2w[idx]);
    s1w[idx] = f2bf(u1);       // w1c[t] = u before update
    s2w[idx] = f2bf(u2);
    m1 = g*m1 + g1v;
    m2 = g*m2 + g2v;
    u1 = dg*u1 + m1;
    u2 = dg*u2 + m2;
  }
}

// ---------------------------------------------------------------------------
// K6: retrieval: pred = silu(q@w1c)@w2c, rmsnorm * (gamma+1) * gate -> outp (bf16)
// ---------------------------------------------------------------------------
__global__ __launch_bounds__(256) void k_retr(const u16* __restrict__ qin,
    const u16* __restrict__ w1c, const u16* __restrict__ w2c,
    const float* __restrict__ gate, const float* __restrict__ gamma,
    u16* __restrict__ outp)
{
  __shared__ u16 qs[64][136];
  __shared__ u16 As[64][136];
  __shared__ u16 Ws[128][136];
  __shared__ float Ps[64][132];
  const int blk = blockIdx.x;
  const int bhi = blk >> 6, ci = blk & 63;
  const int b = bhi >> 2, hd = bhi & 3;
  const int tid = threadIdx.x;
  const size_t rowbase = (size_t)b*4096 + (size_t)ci*64;

  #pragma unroll
  for (int rep=0;rep<4;rep++){
    int lin = rep*2048 + tid*8;
    int i = lin >> 7, d = lin & 127;
    *(uint4*)&qs[i][d] = *(const uint4*)(qin + (rowbase + i)*512 + hd*128 + d);
  }
  const u16* w1 = w1c + (size_t)blk*16384;
  #pragma unroll
  for (int rep=0;rep<8;rep++){
    int lin = rep*2048 + tid*8;
    *(uint4*)&Ws[lin>>7][lin&127] = *(const uint4*)(w1 + lin);
  }
  __syncthreads();

  const int i = tid >> 2, jg = tid & 3;
  // Hq = q @ w1 ; A = silu(Hq)
  {
    float acc[4][8] = {};
    #pragma unroll 2
    for (int d=0; d<128; d++){
      float a = bf2f(qs[i][d]);
      #pragma unroll
      for (int qg=0;qg<4;qg++){
        float w[8]; unpack8(*(const uint4*)&Ws[d][qg*32+jg*8], w);
        #pragma unroll
        for (int jv=0;jv<8;jv++) acc[qg][jv] = fmaf(a, w[jv], acc[qg][jv]);
      }
    }
    #pragma unroll
    for (int qg=0;qg<4;qg++){
      float av[8];
      #pragma unroll
      for (int jv=0;jv<8;jv++){ float h = acc[qg][jv]; av[jv] = h*sigm(h); }
      *(uint4*)&As[i][qg*32+jg*8] = pack8(av);
    }
  }
  __syncthreads();
  const u16* w2 = w2c + (size_t)blk*16384;
  #pragma unroll
  for (int rep=0;rep<8;rep++){
    int lin = rep*2048 + tid*8;
    *(uint4*)&Ws[lin>>7][lin&127] = *(const uint4*)(w2 + lin);
  }
  __syncthreads();
  // P = A @ w2
  {
    float acc[4][8] = {};
    #pragma unroll 2
    for (int d=0; d<128; d++){
      float a = bf2f(As[i][d]);
      #pragma unroll
      for (int qg=0;qg<4;qg++){
        float w[8]; unpack8(*(const uint4*)&Ws[d][qg*32+jg*8], w);
        #pragma unroll
        for (int jv=0;jv<8;jv++) acc[qg][jv] = fmaf(a, w[jv], acc[qg][jv]);
      }
    }
    #pragma unroll
    for (int qg=0;qg<4;qg++){
      *(float4*)&Ps[i][qg*32+jg*8]   = *(float4*)&acc[qg][0];
      *(float4*)&Ps[i][qg*32+jg*8+4] = *(float4*)&acc[qg][4];
    }
  }
  __syncthreads();

  // epilogue: per-row rmsnorm * (gamma+1) * gate
  int wv = tid >> 6, lane = tid & 63;
  #pragma unroll 1
  for (int rr=0; rr<16; rr++){
    int ir = wv*16 + rr;
    float v0 = Ps[ir][lane*2], v1 = Ps[ir][lane*2+1];
    float ssq = v0*v0 + v1*v1;
    #pragma unroll
    for (int o=32;o>=1;o>>=1) ssq += __shfl_xor(ssq, o, 64);
    float inv = rsqrtf(ssq*(1.0f/128.0f) + 1e-6f);
    size_t token = rowbase + ir;
    float gt = gate[token*4 + hd];
    int j0 = lane*2;
    float o0 = v0*inv*(gamma[hd*128+j0]   + 1.0f)*gt;
    float o1 = v1*inv*(gamma[hd*128+j0+1] + 1.0f)*gt;
    *(u32*)(outp + token*512 + hd*128 + j0) = (u32)f2bf(o0) | ((u32)f2bf(o1)<<16);
  }
}

// ---------------------------------------------------------------------------
extern "C" void kernel_launch(void* const* d_in, const int* in_sizes, int n_in,
                              void* d_out, int out_size, void* d_ws, size_t ws_size,
                              hipStream_t stream)
{
  const float* seq    = (const float*)d_in[0];
  const float* gstore = (const float*)d_in[1];
  const float* gret   = (const float*)d_in[2];
  const float* W_q    = (const float*)d_in[3];
  const float* W_kv   = (const float*)d_in[4];
  const float* W_step = (const float*)d_in[5];
  const float* W_mom  = (const float*)d_in[6];
  const float* W_dec  = (const float*)d_in[7];
  const float* W_gate = (const float*)d_in[8];
  const float* gamma  = (const float*)d_in[9];
  const float* W_o    = (const float*)d_in[10];
  const float* MW1    = (const float*)d_in[11];
  const float* MW2    = (const float*)d_in[12];
  float* out = (float*)d_out;

  const size_t NS = (size_t)16384*512;     // tokens * dim
  const size_t NG = (size_t)16*64*16384;   // grad elements
  size_t need = NS*2*3 + NS*2*2 + NG*2*2 + 2*(size_t)16384*4*4 + 2*4096;
  if (ws_size < need) return;              // diagnostic: output stays zero

  char* ws = (char*)d_ws;
  u16* s_bf = (u16*)ws; ws += NS*2;        // s, later reused as outp
  u16* r_bf = (u16*)ws; ws += NS*2;
  u16* kv_bf= (u16*)ws; ws += 2*NS*2;
  u16* q_bf = (u16*)ws; ws += NS*2;
  u16* s1   = (u16*)ws; ws += NG*2;        // later w1c (aliased in k_scan)
  u16* s2   = (u16*)ws; ws += NG*2;        // later w2c
  float* lr   = (float*)ws; ws += (size_t)16384*4*4;
  float* gatep= (float*)ws; ws += (size_t)16384*4*4;
  float* momv = (float*)ws; ws += 1024*4;
  float* dgv  = (float*)ws; ws += 1024*4;
  u16* outp = s_bf;                        // s dead after kv-gemm

  k_token<<<4096, 256, 0, stream>>>(seq, gstore, gret, W_step, W_gate, s_bf, r_bf, lr, gatep);
  k_chunk<<<256, 256, 0, stream>>>(s_bf, W_dec, W_mom, momv, dgv);
  k_gemm<true><<<dim3(8,128), 256, 0, stream>>>(s_bf, W_kv, kv_bf, 512, 512, 1024, 1024);
  k_gemm<true><<<dim3(4,128), 256, 0, stream>>>(r_bf, W_q, q_bf, 512, 512, 512, 512);
  k_grad<<<1024, 256, 0, stream>>>(kv_bf, lr, MW1, MW2, s1, s2);
  k_scan<<<1024, 256, 0, stream>>>(momv, dgv, MW1, MW2, s1, s2);
  k_retr<<<1024, 256, 0, stream>>>(q_bf, s1, s2, gatep, gamma, outp);
  k_gemm<false><<<dim3(4,128), 256, 0, stream>>>(outp, W_o, out, 512, 512, 512, 512);
}

// Round 3
// 227.104 us; speedup vs baseline: 4.0305x; 4.0305x over previous
//
#include <hip/hip_runtime.h>

typedef unsigned short u16;
typedef unsigned int u32;
typedef __attribute__((ext_vector_type(8))) short s16x8;
typedef __attribute__((ext_vector_type(4))) float f32x4;

#define DEV __device__ __forceinline__
#define MFMA16(a,b,c) __builtin_amdgcn_mfma_f32_16x16x32_bf16(a,b,c,0,0,0)

DEV float bf2f(u16 x){ u32 u=((u32)x)<<16; float f; __builtin_memcpy(&f,&u,4); return f; }
DEV u16 f2bf(float f){ u32 u; __builtin_memcpy(&u,&f,4); u32 r=u+0x7FFFu+((u>>16)&1u); return (u16)(r>>16); }
DEV uint4 pack8(const float* f){
  uint4 v;
  v.x=(u32)f2bf(f[0])|((u32)f2bf(f[1])<<16);
  v.y=(u32)f2bf(f[2])|((u32)f2bf(f[3])<<16);
  v.z=(u32)f2bf(f[4])|((u32)f2bf(f[5])<<16);
  v.w=(u32)f2bf(f[6])|((u32)f2bf(f[7])<<16);
  return v;
}
DEV float sigm(float x){ return 1.0f/(1.0f+__expf(-x)); }

// ---------------------------------------------------------------------------
// k_trans: dst[n][k] = bf16(src[k][n]).  grid (Nn/64, K/64), 256 thr.
// ---------------------------------------------------------------------------
__global__ __launch_bounds__(256) void k_trans(const float* __restrict__ src,
    u16* __restrict__ dst, int K, int Nn)
{
  __shared__ float ld[64][65];
  int n0 = blockIdx.x*64, k0 = blockIdx.y*64;
  int tid = threadIdx.x;
  #pragma unroll
  for (int rr=0; rr<4; rr++){
    int kk = rr*16 + (tid>>4);
    int nn = (tid&15)*4;
    float4 v = *(const float4*)(src + (size_t)(k0+kk)*Nn + n0 + nn);
    ld[kk][nn]=v.x; ld[kk][nn+1]=v.y; ld[kk][nn+2]=v.z; ld[kk][nn+3]=v.w;
  }
  __syncthreads();
  int nn2 = tid>>2, kb = (tid&3)*16;
  float o[16];
  #pragma unroll
  for (int j=0;j<16;j++) o[j] = ld[kb+j][nn2];
  u16* dp = dst + (size_t)(n0+nn2)*K + k0 + kb;
  *(uint4*)dp     = pack8(&o[0]);
  *(uint4*)(dp+8) = pack8(&o[8]);
}

// k_conv: plain fp32 -> bf16. grid*256*8 elems.
__global__ __launch_bounds__(256) void k_conv(const float* __restrict__ src,
    u16* __restrict__ dst)
{
  int e = (blockIdx.x*256 + threadIdx.x)*8;
  float f[8];
  *(float4*)&f[0] = *(const float4*)(src+e);
  *(float4*)&f[4] = *(const float4*)(src+e+4);
  *(uint4*)(dst+e) = pack8(f);
}

// ---------------------------------------------------------------------------
// K1: per-token rmsnorm -> s, r (bf16), lr, gate. one wave per token.
// ---------------------------------------------------------------------------
__global__ __launch_bounds__(256) void k_token(const float* __restrict__ seq,
    const float* __restrict__ gs, const float* __restrict__ gr,
    const float* __restrict__ Wstep, const float* __restrict__ Wgate,
    u16* __restrict__ s, u16* __restrict__ r,
    float* __restrict__ lr, float* __restrict__ gate)
{
  int wv = threadIdx.x >> 6, lane = threadIdx.x & 63;
  int token = blockIdx.x*4 + wv;
  const float* row = seq + (size_t)token*512;
  float x[8];
  *(float4*)&x[0] = *(const float4*)(row + lane*8);
  *(float4*)&x[4] = *(const float4*)(row + lane*8 + 4);
  float ss = 0.f;
  #pragma unroll
  for (int j=0;j<8;j++) ss += x[j]*x[j];
  #pragma unroll
  for (int o=32;o>=1;o>>=1) ss += __shfl_xor(ss, o, 64);
  float inv = rsqrtf(ss*(1.0f/512.0f) + 1e-6f);
  float al[4] = {0,0,0,0}, ag[4] = {0,0,0,0};
  float sv8[8], rv8[8];
  #pragma unroll
  for (int j=0;j<8;j++){
    int d = lane*8 + j;
    float sn = x[j]*inv;
    float sv = sn*gs[d];
    float rv = sn*gr[d];
    sv8[j]=sv; rv8[j]=rv;
    float4 wst = *(const float4*)(Wstep + d*4);
    float4 wgt = *(const float4*)(Wgate + d*4);
    al[0]+=sv*wst.x; al[1]+=sv*wst.y; al[2]+=sv*wst.z; al[3]+=sv*wst.w;
    ag[0]+=rv*wgt.x; ag[1]+=rv*wgt.y; ag[2]+=rv*wgt.z; ag[3]+=rv*wgt.w;
  }
  *(uint4*)(s + (size_t)token*512 + lane*8) = pack8(sv8);
  *(uint4*)(r + (size_t)token*512 + lane*8) = pack8(rv8);
  #pragma unroll
  for (int o=32;o>=1;o>>=1){
    #pragma unroll
    for (int h=0;h<4;h++){ al[h] += __shfl_xor(al[h], o, 64); ag[h] += __shfl_xor(ag[h], o, 64); }
  }
  if (lane == 0){
    #pragma unroll
    for (int h=0;h<4;h++){
      lr[(size_t)token*4 + h]   = sigm(al[h]);
      gate[(size_t)token*4 + h] = sigm(ag[h]);
    }
  }
}

// ---------------------------------------------------------------------------
// K2: chunk means -> decay/mom gates.
// ---------------------------------------------------------------------------
__global__ __launch_bounds__(256) void k_chunk(const u16* __restrict__ s,
    const float* __restrict__ Wdec, const float* __restrict__ Wmom,
    float* __restrict__ momv, float* __restrict__ dgv)
{
  int b = blockIdx.x >> 6, ci = blockIdx.x & 63;
  int d = threadIdx.x;
  size_t base = ((size_t)b*4096 + (size_t)ci*64)*512;
  float a0 = 0.f, a1 = 0.f;
  #pragma unroll 4
  for (int t=0;t<64;t++){
    a0 += bf2f(s[base + (size_t)t*512 + d]);
    a1 += bf2f(s[base + (size_t)t*512 + d + 256]);
  }
  a0 *= (1.0f/64.0f); a1 *= (1.0f/64.0f);
  __shared__ float red[8][256];
  #pragma unroll
  for (int h=0;h<4;h++){
    red[h][d]   = a0*Wdec[d*4+h] + a1*Wdec[(d+256)*4+h];
    red[4+h][d] = a0*Wmom[d*4+h] + a1*Wmom[(d+256)*4+h];
  }
  __syncthreads();
  if (d < 8){
    float sum = 0.f;
    #pragma unroll 8
    for (int k=0;k<256;k++) sum += red[d][k];
    int h = d & 3;
    if (d < 4) dgv[((size_t)(b*4+h))*64 + ci] = 1.0f - sigm(sum);
    else       momv[((size_t)(b*4+h))*64 + ci] = sigm(sum);
  }
}

// ---------------------------------------------------------------------------
// K3: MFMA GEMM. A[M][K] bf16 (K contig), Bt[N][K] bf16 (K contig), C[M][N].
// 128x128 tile, 4 waves (2x2), each 64x64. K staged in 64-chunks.
// ---------------------------------------------------------------------------
template<bool OUT_BF>
__global__ __launch_bounds__(256) void k_gemm(const u16* __restrict__ A,
    const u16* __restrict__ Bt, void* __restrict__ Cv, int K, int ldc)
{
  __shared__ u16 sA[128*72];
  __shared__ u16 sB[128*72];
  const int tid = threadIdx.x;
  const int wv = tid>>6, lane = tid&63, lrow = lane&15, lk = lane>>4;
  const int wm = (wv>>1)*64, wn = (wv&1)*64;
  const int rowbase = blockIdx.y*128, colbase = blockIdx.x*128;
  f32x4 acc[4][4] = {};
  for (int kc = 0; kc < K; kc += 64){
    __syncthreads();
    #pragma unroll
    for (int rep=0;rep<4;rep++){
      int lin = rep*2048 + tid*8;
      int rr = lin>>6, kk = lin&63;
      *(uint4*)&sA[rr*72+kk] = *(const uint4*)(A + (size_t)(rowbase+rr)*K + kc + kk);
      *(uint4*)&sB[rr*72+kk] = *(const uint4*)(Bt + (size_t)(colbase+rr)*K + kc + kk);
    }
    __syncthreads();
    #pragma unroll
    for (int k0=0;k0<2;k0++){
      s16x8 a[4], b[4];
      #pragma unroll
      for (int m=0;m<4;m++) a[m] = *(const s16x8*)&sA[(wm+m*16+lrow)*72 + k0*32 + lk*8];
      #pragma unroll
      for (int n=0;n<4;n++) b[n] = *(const s16x8*)&sB[(wn+n*16+lrow)*72 + k0*32 + lk*8];
      #pragma unroll
      for (int m=0;m<4;m++)
        #pragma unroll
        for (int n=0;n<4;n++)
          acc[m][n] = MFMA16(a[m], b[n], acc[m][n]);
    }
  }
  #pragma unroll
  for (int m=0;m<4;m++)
    #pragma unroll
    for (int n=0;n<4;n++)
      #pragma unroll
      for (int r=0;r<4;r++){
        int row = rowbase + wm + m*16 + lk*4 + r;
        int col = colbase + wn + n*16 + lrow;
        float v = acc[m][n][r];
        if (OUT_BF) ((u16*)Cv)[(size_t)row*ldc + col] = f2bf(v);
        else        ((float*)Cv)[(size_t)row*ldc + col] = v;
      }
}

// ---------------------------------------------------------------------------
// K4: per-chunk gradient, all matmuls via MFMA. one block (4 waves) per (bh,chunk).
// Outputs s1t [d_h][d_in], s2t [d_out][d_h] (transposed storage).
// ---------------------------------------------------------------------------
__global__ __launch_bounds__(256) void k_grad(const u16* __restrict__ kv,
    const float* __restrict__ lr, const u16* __restrict__ W1t,
    const u16* __restrict__ W2t, const u16* __restrict__ W2s,
    u16* __restrict__ s1, u16* __restrict__ s2)
{
  __shared__ u16 sA[64*136];    // kcs (row-major) -> dPs (row-major)
  __shared__ u16 sB[128*72];    // As (row-major [64][136] fits) -> dHt [d][i]
  __shared__ u16 sC[128*72];    // kct [d][i]
  __shared__ u16 sD[128*72];    // Ast [d][i]
  __shared__ u16 sE[128*72];    // dPt [d][i]
  __shared__ u16 sW1[128*136];  // W1t -> W2s
  __shared__ u16 sW2[128*136];  // W2t
  __shared__ float lrs[64];

  const int blk = blockIdx.x;
  const int bhi = blk >> 6, ci = blk & 63;
  const int b = bhi >> 2, hd = bhi & 3;
  const int tid = threadIdx.x;
  const int wv = tid>>6, lane = tid&63, lrow = lane&15, lk = lane>>4;
  const int nb = wv*32;
  const size_t rowbase = (size_t)b*4096 + (size_t)ci*64;

  // ---- stage0: kc (+transpose), W1t, W2t, lrs
  #pragma unroll
  for (int rep=0;rep<4;rep++){
    int lin = rep*2048 + tid*8;
    int i = lin >> 7, d = lin & 127;
    union { uint4 v; u16 h[8]; } u;
    u.v = *(const uint4*)(kv + (rowbase + i)*1024 + hd*128 + d);
    *(uint4*)&sA[i*136 + d] = u.v;
    #pragma unroll
    for (int j=0;j<8;j++) sC[(d+j)*72 + i] = u.h[j];
  }
  #pragma unroll
  for (int rep=0;rep<8;rep++){
    int lin = rep*2048 + tid*8;
    *(uint4*)&sW1[(lin>>7)*136 + (lin&127)] = *(const uint4*)(W1t + lin);
    *(uint4*)&sW2[(lin>>7)*136 + (lin&127)] = *(const uint4*)(W2t + lin);
  }
  if (tid < 64) lrs[tid] = lr[(rowbase + tid)*4 + hd] * (2.0f/128.0f);
  __syncthreads();

  float spv[4][2][4];

  // ---- mm1: H = kc @ W1 ; A = silu(H), spv = silu'(H)
  {
    f32x4 acc[4][2] = {};
    #pragma unroll
    for (int k0=0;k0<4;k0++){
      s16x8 a[4], bfr[2];
      #pragma unroll
      for (int m=0;m<4;m++) a[m] = *(const s16x8*)&sA[(m*16+lrow)*136 + k0*32 + lk*8];
      #pragma unroll
      for (int n=0;n<2;n++) bfr[n] = *(const s16x8*)&sW1[(nb+n*16+lrow)*136 + k0*32 + lk*8];
      #pragma unroll
      for (int m=0;m<4;m++)
        #pragma unroll
        for (int n=0;n<2;n++) acc[m][n] = MFMA16(a[m], bfr[n], acc[m][n]);
    }
    #pragma unroll
    for (int m=0;m<4;m++)
      #pragma unroll
      for (int n=0;n<2;n++){
        int col = nb + n*16 + lrow;
        int row0 = m*16 + lk*4;
        u16 av4[4];
        #pragma unroll
        for (int r=0;r<4;r++){
          float h = acc[m][n][r];
          float sg = sigm(h);
          float av = h*sg;
          spv[m][n][r] = sg*(1.0f + h*(1.0f - sg));
          av4[r] = f2bf(av);
          sB[(row0+r)*136 + col] = av4[r];        // As row-major
        }
        *(uint2*)&sD[col*72 + row0] = make_uint2(  // Ast [d_h][i]
          (u32)av4[0] | ((u32)av4[1]<<16), (u32)av4[2] | ((u32)av4[3]<<16));
      }
  }
  __syncthreads();

  // ---- stage W2s into sW1 (W1t dead); mm2: P = A @ W2 ; dP
  #pragma unroll
  for (int rep=0;rep<8;rep++){
    int lin = rep*2048 + tid*8;
    *(uint4*)&sW1[(lin>>7)*136 + (lin&127)] = *(const uint4*)(W2s + lin);
  }
  {
    f32x4 acc[4][2] = {};
    #pragma unroll
    for (int k0=0;k0<4;k0++){
      s16x8 a[4], bfr[2];
      #pragma unroll
      for (int m=0;m<4;m++) a[m] = *(const s16x8*)&sB[(m*16+lrow)*136 + k0*32 + lk*8];
      #pragma unroll
      for (int n=0;n<2;n++) bfr[n] = *(const s16x8*)&sW2[(nb+n*16+lrow)*136 + k0*32 + lk*8];
      #pragma unroll
      for (int m=0;m<4;m++)
        #pragma unroll
        for (int n=0;n<2;n++) acc[m][n] = MFMA16(a[m], bfr[n], acc[m][n]);
    }
    __syncthreads();   // As fully read; also W2s staged (needed next phase)
    #pragma unroll
    for (int m=0;m<4;m++)
      #pragma unroll
      for (int n=0;n<2;n++){
        int col = nb + n*16 + lrow;
        int row0 = m*16 + lk*4;
        u16 dp4[4];
        #pragma unroll
        for (int r=0;r<4;r++){
          int row = row0 + r;
          float vv = bf2f(kv[(rowbase+row)*1024 + 512 + hd*128 + col]);
          float dp = lrs[row]*(acc[m][n][r] - vv);
          dp4[r] = f2bf(dp);
          sA[row*136 + col] = dp4[r];             // dPs row-major (kcs dead)
        }
        *(uint2*)&sE[col*72 + row0] = make_uint2(  // dPt [d_out][i]
          (u32)dp4[0] | ((u32)dp4[1]<<16), (u32)dp4[2] | ((u32)dp4[3]<<16));
      }
  }
  __syncthreads();

  // ---- mm3: dA = dP @ W2^T ; dH = spv * dA -> dHt (overwrites As slot)
  {
    f32x4 acc[4][2] = {};
    #pragma unroll
    for (int k0=0;k0<4;k0++){
      s16x8 a[4], bfr[2];
      #pragma unroll
      for (int m=0;m<4;m++) a[m] = *(const s16x8*)&sA[(m*16+lrow)*136 + k0*32 + lk*8];
      #pragma unroll
      for (int n=0;n<2;n++) bfr[n] = *(const s16x8*)&sW1[(nb+n*16+lrow)*136 + k0*32 + lk*8];
      #pragma unroll
      for (int m=0;m<4;m++)
        #pragma unroll
        for (int n=0;n<2;n++) acc[m][n] = MFMA16(a[m], bfr[n], acc[m][n]);
    }
    __syncthreads();   // ensure everyone done reading As slot region? (As dead since mm2) -- protects sB overwrite vs mm3 readers of sA/sW1 only; keep for safety before sB write
    #pragma unroll
    for (int m=0;m<4;m++)
      #pragma unroll
      for (int n=0;n<2;n++){
        int col = nb + n*16 + lrow;
        int row0 = m*16 + lk*4;
        u16 dh4[4];
        #pragma unroll
        for (int r=0;r<4;r++) dh4[r] = f2bf(spv[m][n][r]*acc[m][n][r]);
        *(uint2*)&sB[col*72 + row0] = make_uint2(  // dHt [d_h][i]
          (u32)dh4[0] | ((u32)dh4[1]<<16), (u32)dh4[2] | ((u32)dh4[3]<<16));
      }
  }
  __syncthreads();

  const size_t outbase = (size_t)blk * 16384;

  // ---- mm4: s2t[d_out][d_h] = -(dP^T @ A):  A-op = dPt, B-op = Ast
  {
    f32x4 acc[8][2] = {};
    #pragma unroll
    for (int k0=0;k0<2;k0++){
      s16x8 a[8], bfr[2];
      #pragma unroll
      for (int m=0;m<8;m++) a[m] = *(const s16x8*)&sE[(m*16+lrow)*72 + k0*32 + lk*8];
      #pragma unroll
      for (int n=0;n<2;n++) bfr[n] = *(const s16x8*)&sD[(nb+n*16+lrow)*72 + k0*32 + lk*8];
      #pragma unroll
      for (int m=0;m<8;m++)
        #pragma unroll
        for (int n=0;n<2;n++) acc[m][n] = MFMA16(a[m], bfr[n], acc[m][n]);
    }
    #pragma unroll
    for (int m=0;m<8;m++)
      #pragma unroll
      for (int n=0;n<2;n++)
        #pragma unroll
        for (int r=0;r<4;r++){
          int row = m*16 + lk*4 + r;       // d_out
          int col = nb + n*16 + lrow;      // d_h
          s2[outbase + (size_t)row*128 + col] = f2bf(-acc[m][n][r]);
        }
  }
  // ---- mm5: s1t[d_h][d_in] = -(dH^T @ kc):  A-op = dHt, B-op = kct
  {
    f32x4 acc[8][2] = {};
    #pragma unroll
    for (int k0=0;k0<2;k0++){
      s16x8 a[8], bfr[2];
      #pragma unroll
      for (int m=0;m<8;m++) a[m] = *(const s16x8*)&sB[(m*16+lrow)*72 + k0*32 + lk*8];
      #pragma unroll
      for (int n=0;n<2;n++) bfr[n] = *(const s16x8*)&sC[(nb+n*16+lrow)*72 + k0*32 + lk*8];
      #pragma unroll
      for (int m=0;m<8;m++)
        #pragma unroll
        for (int n=0;n<2;n++) acc[m][n] = MFMA16(a[m], bfr[n], acc[m][n]);
    }
    #pragma unroll
    for (int m=0;m<8;m++)
      #pragma unroll
      for (int n=0;n<2;n++)
        #pragma unroll
        for (int r=0;r<4;r++){
          int row = m*16 + lk*4 + r;       // d_h
          int col = nb + n*16 + lrow;      // d_in
          s1[outbase + (size_t)row*128 + col] = f2bf(-acc[m][n][r]);
        }
  }
}

// ---------------------------------------------------------------------------
// K5: fused momentum + decay scans (transposed element layout; elementwise).
// w1c aliases s1, w2c aliases s2. Init reads MW transposed.
// ---------------------------------------------------------------------------
__global__ __launch_bounds__(256) void k_scan(const float* __restrict__ momv,
    const float* __restrict__ dgv, const float* __restrict__ MW1,
    const float* __restrict__ MW2, u16* __restrict__ s1w, u16* __restrict__ s2w)
{
  int bhi = blockIdx.x >> 6, eb = blockIdx.x & 63;
  int e = eb*256 + threadIdx.x;
  float u1 = MW1[(e&127)*128 + (e>>7)];
  float u2 = MW2[(e&127)*128 + (e>>7)];
  float m1 = 0.f, m2 = 0.f;
  size_t base = (size_t)bhi*64*16384 + e;
  #pragma unroll 1
  for (int t=0; t<64; t++){
    float g  = momv[bhi*64 + t];
    float dg = dgv[bhi*64 + t];
    size_t idx = base + (size_t)t*16384;
    float g1v = bf2f(s1w[idx]);
    float g2v = bf2f(s2w[idx]);
    s1w[idx] = f2bf(u1);
    s2w[idx] = f2bf(u2);
    m1 = g*m1 + g1v;
    m2 = g*m2 + g2v;
    u1 = dg*u1 + m1;
    u2 = dg*u2 + m2;
  }
}

// ---------------------------------------------------------------------------
// K6: retrieval via MFMA: P = silu(q@w1c)@w2c, rmsnorm*(gamma+1)*gate -> outp
// w1c stored [d_h][d_in], w2c stored [d_out][d_h] -> both are ready Bt layouts.
// ---------------------------------------------------------------------------
__global__ __launch_bounds__(256) void k_retr(const u16* __restrict__ qin,
    const u16* __restrict__ w1c, const u16* __restrict__ w2c,
    const float* __restrict__ gate, const float* __restrict__ gamma,
    u16* __restrict__ outp)
{
  __shared__ u16 sQ[64*136];   // qs -> Ps (bf16 out)
  __shared__ u16 sAs[64*136];  // A2
  __shared__ u16 sW[128*136];  // w1ct -> w2ct
  __shared__ float rsum[4][64];
  __shared__ float gts[64];
  const int blk = blockIdx.x;
  const int bhi = blk >> 6, ci = blk & 63;
  const int b = bhi >> 2, hd = bhi & 3;
  const int tid = threadIdx.x;
  const int wv = tid>>6, lane = tid&63, lrow = lane&15, lk = lane>>4;
  const int nb = wv*32;
  const size_t rowbase = (size_t)b*4096 + (size_t)ci*64;

  #pragma unroll
  for (int rep=0;rep<4;rep++){
    int lin = rep*2048 + tid*8;
    int i = lin >> 7, d = lin & 127;
    *(uint4*)&sQ[i*136+d] = *(const uint4*)(qin + (rowbase + i)*512 + hd*128 + d);
  }
  const u16* w1 = w1c + (size_t)blk*16384;
  #pragma unroll
  for (int rep=0;rep<8;rep++){
    int lin = rep*2048 + tid*8;
    *(uint4*)&sW[(lin>>7)*136 + (lin&127)] = *(const uint4*)(w1 + lin);
  }
  if (tid < 64) gts[tid] = gate[(rowbase + tid)*4 + hd];
  __syncthreads();

  // mm1: Hq = q @ w1 ; A2 = silu
  {
    f32x4 acc[4][2] = {};
    #pragma unroll
    for (int k0=0;k0<4;k0++){
      s16x8 a[4], bfr[2];
      #pragma unroll
      for (int m=0;m<4;m++) a[m] = *(const s16x8*)&sQ[(m*16+lrow)*136 + k0*32 + lk*8];
      #pragma unroll
      for (int n=0;n<2;n++) bfr[n] = *(const s16x8*)&sW[(nb+n*16+lrow)*136 + k0*32 + lk*8];
      #pragma unroll
      for (int m=0;m<4;m++)
        #pragma unroll
        for (int n=0;n<2;n++) acc[m][n] = MFMA16(a[m], bfr[n], acc[m][n]);
    }
    #pragma unroll
    for (int m=0;m<4;m++)
      #pragma unroll
      for (int n=0;n<2;n++){
        int col = nb + n*16 + lrow;
        #pragma unroll
        for (int r=0;r<4;r++){
          float h = acc[m][n][r];
          sAs[(m*16+lk*4+r)*136 + col] = f2bf(h*sigm(h));
        }
      }
  }
  __syncthreads();
  const u16* w2 = w2c + (size_t)blk*16384;
  #pragma unroll
  for (int rep=0;rep<8;rep++){
    int lin = rep*2048 + tid*8;
    *(uint4*)&sW[(lin>>7)*136 + (lin&127)] = *(const uint4*)(w2 + lin);
  }
  __syncthreads();

  // mm2: P = A2 @ w2
  f32x4 acc[4][2] = {};
  #pragma unroll
  for (int k0=0;k0<4;k0++){
    s16x8 a[4], bfr[2];
    #pragma unroll
    for (int m=0;m<4;m++) a[m] = *(const s16x8*)&sAs[(m*16+lrow)*136 + k0*32 + lk*8];
    #pragma unroll
    for (int n=0;n<2;n++) bfr[n] = *(const s16x8*)&sW[(nb+n*16+lrow)*136 + k0*32 + lk*8];
    #pragma unroll
    for (int m=0;m<4;m++)
      #pragma unroll
      for (int n=0;n<2;n++) acc[m][n] = MFMA16(a[m], bfr[n], acc[m][n]);
  }
  // partial row-sums of squares (32 cols per wave)
  #pragma unroll
  for (int m=0;m<4;m++){
    #pragma unroll
    for (int r=0;r<4;r++){
      float p = acc[m][0][r]*acc[m][0][r] + acc[m][1][r]*acc[m][1][r];
      p += __shfl_xor(p, 1, 64);
      p += __shfl_xor(p, 2, 64);
      p += __shfl_xor(p, 4, 64);
      p += __shfl_xor(p, 8, 64);
      if (lrow == 0) rsum[wv][m*16 + lk*4 + r] = p;
    }
  }
  __syncthreads();
  float gm[2];
  #pragma unroll
  for (int n=0;n<2;n++) gm[n] = gamma[hd*128 + nb + n*16 + lrow] + 1.0f;
  #pragma unroll
  for (int m=0;m<4;m++)
    #pragma unroll
    for (int r=0;r<4;r++){
      int row = m*16 + lk*4 + r;
      float sum = rsum[0][row] + rsum[1][row] + rsum[2][row] + rsum[3][row];
      float inv = rsqrtf(sum*(1.0f/128.0f) + 1e-6f) * gts[row];
      #pragma unroll
      for (int n=0;n<2;n++){
        int col = nb + n*16 + lrow;
        sQ[row*136 + col] = f2bf(acc[m][n][r]*inv*gm[n]);
      }
    }
  __syncthreads();
  #pragma unroll
  for (int rep=0;rep<4;rep++){
    int lin = rep*2048 + tid*8;
    int i = lin >> 7, d = lin & 127;
    *(uint4*)(outp + (rowbase+i)*512 + hd*128 + d) = *(uint4*)&sQ[i*136+d];
  }
}

// ---------------------------------------------------------------------------
extern "C" void kernel_launch(void* const* d_in, const int* in_sizes, int n_in,
                              void* d_out, int out_size, void* d_ws, size_t ws_size,
                              hipStream_t stream)
{
  const float* seq    = (const float*)d_in[0];
  const float* gstore = (const float*)d_in[1];
  const float* gret   = (const float*)d_in[2];
  const float* W_q    = (const float*)d_in[3];
  const float* W_kv   = (const float*)d_in[4];
  const float* W_step = (const float*)d_in[5];
  const float* W_mom  = (const float*)d_in[6];
  const float* W_dec  = (const float*)d_in[7];
  const float* W_gate = (const float*)d_in[8];
  const float* gamma  = (const float*)d_in[9];
  const float* W_o    = (const float*)d_in[10];
  const float* MW1    = (const float*)d_in[11];
  const float* MW2    = (const float*)d_in[12];
  float* out = (float*)d_out;

  const size_t NS = (size_t)16384*512;
  const size_t NG = (size_t)16*64*16384;
  size_t need = (5*NS + 2*NG + 524288 + 262144 + 262144 + 3*16384)*2
              + (2*65536 + 2048)*4;
  if (ws_size < need) return;

  char* ws = (char*)d_ws;
  u16* s_bf = (u16*)ws; ws += NS*2;        // s; reused as outp after kv-gemm/chunk
  u16* r_bf = (u16*)ws; ws += NS*2;
  u16* kv_bf= (u16*)ws; ws += 2*NS*2;
  u16* q_bf = (u16*)ws; ws += NS*2;
  u16* s1   = (u16*)ws; ws += NG*2;        // -> w1c after k_scan
  u16* s2   = (u16*)ws; ws += NG*2;        // -> w2c
  u16* Wkvt = (u16*)ws; ws += (size_t)524288*2;
  u16* Wqt  = (u16*)ws; ws += (size_t)262144*2;
  u16* Wot  = (u16*)ws; ws += (size_t)262144*2;
  u16* W1tb = (u16*)ws; ws += (size_t)16384*2;
  u16* W2tb = (u16*)ws; ws += (size_t)16384*2;
  u16* W2sb = (u16*)ws; ws += (size_t)16384*2;
  float* lr   = (float*)ws; ws += (size_t)65536*4;
  float* gatep= (float*)ws; ws += (size_t)65536*4;
  float* momv = (float*)ws; ws += 1024*4;
  float* dgv  = (float*)ws; ws += 1024*4;
  u16* outp = s_bf;

  // weight prep
  k_trans<<<dim3(16,8), 256, 0, stream>>>(W_kv, Wkvt, 512, 1024);
  k_trans<<<dim3(8,8),  256, 0, stream>>>(W_q,  Wqt,  512, 512);
  k_trans<<<dim3(8,8),  256, 0, stream>>>(W_o,  Wot,  512, 512);
  k_trans<<<dim3(2,2),  256, 0, stream>>>(MW1,  W1tb, 128, 128);
  k_trans<<<dim3(2,2),  256, 0, stream>>>(MW2,  W2tb, 128, 128);
  k_conv<<<8, 256, 0, stream>>>(MW2, W2sb);

  k_token<<<4096, 256, 0, stream>>>(seq, gstore, gret, W_step, W_gate, s_bf, r_bf, lr, gatep);
  k_chunk<<<256, 256, 0, stream>>>(s_bf, W_dec, W_mom, momv, dgv);
  k_gemm<true><<<dim3(8,128), 256, 0, stream>>>(s_bf, Wkvt, kv_bf, 512, 1024);
  k_gemm<true><<<dim3(4,128), 256, 0, stream>>>(r_bf, Wqt, q_bf, 512, 512);
  k_grad<<<1024, 256, 0, stream>>>(kv_bf, lr, W1tb, W2tb, W2sb, s1, s2);
  k_scan<<<1024, 256, 0, stream>>>(momv, dgv, MW1, MW2, s1, s2);
  k_retr<<<1024, 256, 0, stream>>>(q_bf, s1, s2, gatep, gamma, outp);
  k_gemm<false><<<dim3(4,128), 256, 0, stream>>>(outp, Wot, out, 512, 512);
}